// Round 4
// baseline (185.350 us; speedup 1.0000x reference)
//
#include <hip/hip_runtime.h>

#define N_NODES 50000
#define N_EDGES 600000
#define D 128
#define NC 40
#define SCAN_BLK 256
#define N_SCAN_BLKS ((N_NODES + SCAN_BLK - 1) / SCAN_BLK)  // 196 <= 256

// ---------------- degree ----------------

__global__ void k_count_deg(const int* __restrict__ dst, int* __restrict__ deg, int nE) {
    int e = blockIdx.x * blockDim.x + threadIdx.x;
    if (e < nE) atomicAdd(&deg[dst[e]], 1);
}

// ---------------- scan (3-kernel) + dinv folded into pass 1 ----------------

__global__ void k_scan1(const int* __restrict__ deg, int* __restrict__ excl,
                        int* __restrict__ blk_sum, float* __restrict__ dinv, int nN) {
    __shared__ int lds[SCAN_BLK];
    int t = threadIdx.x;
    int i = blockIdx.x * SCAN_BLK + t;
    int v = (i < nN) ? deg[i] : 0;
    if (i < nN) dinv[i] = rsqrtf((float)v + 1.0f);  // +1 = self-loop
    lds[t] = v;
    __syncthreads();
    for (int offs = 1; offs < SCAN_BLK; offs <<= 1) {
        int add = (t >= offs) ? lds[t - offs] : 0;
        __syncthreads();
        lds[t] += add;
        __syncthreads();
    }
    if (i < nN) excl[i] = lds[t] - v;
    if (t == SCAN_BLK - 1) blk_sum[blockIdx.x] = lds[t];
}

__global__ void k_scan2(const int* __restrict__ blk_sum, int* __restrict__ blk_off, int nB) {
    __shared__ int lds[SCAN_BLK];
    int t = threadIdx.x;
    int v = (t < nB) ? blk_sum[t] : 0;
    lds[t] = v;
    __syncthreads();
    for (int offs = 1; offs < SCAN_BLK; offs <<= 1) {
        int add = (t >= offs) ? lds[t - offs] : 0;
        __syncthreads();
        lds[t] += add;
        __syncthreads();
    }
    if (t < nB) blk_off[t] = lds[t] - v;
}

__global__ void k_scan3(const int* __restrict__ excl, const int* __restrict__ blk_off,
                        int* __restrict__ row_start, int* __restrict__ cursor, int nN, int nE) {
    int i = blockIdx.x * blockDim.x + threadIdx.x;
    if (i < nN) {
        int r = excl[i] + blk_off[i / SCAN_BLK];
        row_start[i] = r;
        cursor[i] = r;
    }
    if (i == 0) row_start[nN] = nE;
}

// ---------------- CSR fill (by dst), packed {src, w} ----------------

__global__ void k_fill(const int* __restrict__ src, const int* __restrict__ dst,
                       const float* __restrict__ dinv, int* __restrict__ cursor,
                       int2* __restrict__ csr, int nE) {
    int e = blockIdx.x * blockDim.x + threadIdx.x;
    if (e >= nE) return;
    int s = src[e], d = dst[e];
    float w = dinv[s] * dinv[d];
    int pos = atomicAdd(&cursor[d], 1);
    csr[pos] = make_int2(s, __float_as_int(w));
}

// ---------------- fused weights: Wf = W_sgc @ W_cls, bf = b_sgc @ W_cls + b_cls ----

__global__ void k_fuse_w(const float* __restrict__ Wsgc, const float* __restrict__ bsgc,
                         const float* __restrict__ Wcls, const float* __restrict__ bcls,
                         float* __restrict__ Wf, float* __restrict__ bf) {
    int idx = blockIdx.x * blockDim.x + threadIdx.x;
    if (idx < D * NC) {
        int k = idx / NC, c = idx % NC;
        float acc = 0.f;
        for (int j = 0; j < D; j++) acc += Wsgc[k * D + j] * Wcls[j * NC + c];
        Wf[idx] = acc;
    } else if (idx < D * NC + NC) {
        int c = idx - D * NC;
        float acc = bcls[c];
        for (int j = 0; j < D; j++) acc += bsgc[j] * Wcls[j * NC + c];
        bf[c] = acc;
    }
}

// ---------------- projection: z = x @ Wf  (50000x128 @ 128x40), LDS-free ----------------
// 320 threads = 5 waves. Wave w owns output cols [w*8, w*8+8); lane = node within a
// 64-node tile. W reads are wave-uniform (L1 broadcast); x reads stream each lane's
// own row (per-wave working set 8 KB, L1-resident). No LDS, no syncthreads.

__global__ void k_proj(const float* __restrict__ x, const float* __restrict__ Wf,
                       float* __restrict__ z, int nN) {
    int lane = threadIdx.x & 63;
    int wv = threadIdx.x >> 6;            // 0..4
    int node = blockIdx.x * 64 + lane;
    if (node >= nN) return;
    int c0 = wv * 8;
    const float4* xr = reinterpret_cast<const float4*>(x + (size_t)node * D);
    float4 a0 = make_float4(0.f, 0.f, 0.f, 0.f);
    float4 a1 = make_float4(0.f, 0.f, 0.f, 0.f);
#pragma unroll 4
    for (int k4 = 0; k4 < D / 4; k4++) {
        float4 h = xr[k4];
        const float* wr = Wf + (size_t)(k4 * 4) * NC + c0;
        float4 w0a = *reinterpret_cast<const float4*>(wr);
        float4 w0b = *reinterpret_cast<const float4*>(wr + 4);
        float4 w1a = *reinterpret_cast<const float4*>(wr + NC);
        float4 w1b = *reinterpret_cast<const float4*>(wr + NC + 4);
        float4 w2a = *reinterpret_cast<const float4*>(wr + 2 * NC);
        float4 w2b = *reinterpret_cast<const float4*>(wr + 2 * NC + 4);
        float4 w3a = *reinterpret_cast<const float4*>(wr + 3 * NC);
        float4 w3b = *reinterpret_cast<const float4*>(wr + 3 * NC + 4);
        a0.x += h.x * w0a.x; a0.y += h.x * w0a.y; a0.z += h.x * w0a.z; a0.w += h.x * w0a.w;
        a1.x += h.x * w0b.x; a1.y += h.x * w0b.y; a1.z += h.x * w0b.z; a1.w += h.x * w0b.w;
        a0.x += h.y * w1a.x; a0.y += h.y * w1a.y; a0.z += h.y * w1a.z; a0.w += h.y * w1a.w;
        a1.x += h.y * w1b.x; a1.y += h.y * w1b.y; a1.z += h.y * w1b.z; a1.w += h.y * w1b.w;
        a0.x += h.z * w2a.x; a0.y += h.z * w2a.y; a0.z += h.z * w2a.z; a0.w += h.z * w2a.w;
        a1.x += h.z * w2b.x; a1.y += h.z * w2b.y; a1.z += h.z * w2b.z; a1.w += h.z * w2b.w;
        a0.x += h.w * w3a.x; a0.y += h.w * w3a.y; a0.z += h.w * w3a.z; a0.w += h.w * w3a.w;
        a1.x += h.w * w3b.x; a1.y += h.w * w3b.y; a1.z += h.w * w3b.z; a1.w += h.w * w3b.w;
    }
    float* zo = z + (size_t)node * NC + c0;
    *reinterpret_cast<float4*>(zo) = a0;
    *reinterpret_cast<float4*>(zo + 4) = a1;
}

// ---------------- pull propagation on 40-wide features ----------------
// hout[i] = dinv[i]^2 * hin[i] + sum_j w_j * hin[src_j]   (+ optional bias)
// 10 lanes x float4 per node; 6 groups per wave; 24 nodes per 256-thread block.

__global__ void k_pull40(const int* __restrict__ row_start, const int2* __restrict__ csr,
                         const float* __restrict__ dinv,
                         const float* __restrict__ hin, float* __restrict__ hout,
                         const float* __restrict__ bias, int nN) {
    int wave = threadIdx.x >> 6;
    int lane = threadIdx.x & 63;
    int g = lane / 10;            // 0..5, g==6 idle (lanes 60..63)
    int l = lane - g * 10;
    int node = blockIdx.x * 24 + wave * 6 + g;
    if (g >= 6 || node >= nN) return;
    int f = l << 2;               // feat 0..36
    float s = dinv[node];
    s = s * s;
    float4 acc = *reinterpret_cast<const float4*>(hin + (size_t)node * NC + f);
    acc.x *= s; acc.y *= s; acc.z *= s; acc.w *= s;
    int j = row_start[node], end = row_start[node + 1];
    for (; j + 2 <= end; j += 2) {
        int2 e0 = csr[j], e1 = csr[j + 1];
        float w0 = __int_as_float(e0.y), w1 = __int_as_float(e1.y);
        float4 v0 = *reinterpret_cast<const float4*>(hin + (size_t)e0.x * NC + f);
        float4 v1 = *reinterpret_cast<const float4*>(hin + (size_t)e1.x * NC + f);
        acc.x += w0 * v0.x; acc.y += w0 * v0.y; acc.z += w0 * v0.z; acc.w += w0 * v0.w;
        acc.x += w1 * v1.x; acc.y += w1 * v1.y; acc.z += w1 * v1.z; acc.w += w1 * v1.w;
    }
    if (j < end) {
        int2 e0 = csr[j];
        float w0 = __int_as_float(e0.y);
        float4 v0 = *reinterpret_cast<const float4*>(hin + (size_t)e0.x * NC + f);
        acc.x += w0 * v0.x; acc.y += w0 * v0.y; acc.z += w0 * v0.z; acc.w += w0 * v0.w;
    }
    if (bias) {
        float4 b = *reinterpret_cast<const float4*>(bias + f);
        acc.x += b.x; acc.y += b.y; acc.z += b.z; acc.w += b.w;
    }
    *reinterpret_cast<float4*>(hout + (size_t)node * NC + f) = acc;
}

// ---------------- launch ----------------

extern "C" void kernel_launch(void* const* d_in, const int* in_sizes, int n_in,
                              void* d_out, int out_size, void* d_ws, size_t ws_size,
                              hipStream_t stream) {
    const float* x    = (const float*)d_in[0];
    const int*   ei   = (const int*)d_in[1];   // [2, E] flat: row0=src, row1=dst
    const float* Wsgc = (const float*)d_in[2];
    const float* bsgc = (const float*)d_in[3];
    const float* Wcls = (const float*)d_in[4];
    const float* bcls = (const float*)d_in[5];
    float* out = (float*)d_out;

    const int* src = ei;
    const int* dst = ei + N_EDGES;

    char* ws = (char*)d_ws;
    size_t off = 0;
    auto alloc = [&](size_t bytes) -> void* {
        void* p = ws + off;
        off += (bytes + 255) & ~255ull;
        return p;
    };
    int*   deg      = (int*)alloc((size_t)N_NODES * 4);
    float* dinv     = (float*)alloc((size_t)N_NODES * 4);
    int*   excl     = (int*)alloc((size_t)N_NODES * 4);
    int*   blk_sum  = (int*)alloc((size_t)SCAN_BLK * 4);
    int*   blk_off  = (int*)alloc((size_t)SCAN_BLK * 4);
    int*   row_start= (int*)alloc((size_t)(N_NODES + 1) * 4);
    int*   cursor   = (int*)alloc((size_t)N_NODES * 4);
    int2*  csr      = (int2*)alloc((size_t)N_EDGES * 8);
    float* z0       = (float*)alloc((size_t)N_NODES * NC * 4);
    float* z1       = (float*)alloc((size_t)N_NODES * NC * 4);
    float* Wf       = (float*)alloc((size_t)D * NC * 4);
    float* bf       = (float*)alloc((size_t)NC * 4);

    hipMemsetAsync(deg, 0, (size_t)N_NODES * 4, stream);
    k_count_deg<<<(N_EDGES + 255) / 256, 256, 0, stream>>>(dst, deg, N_EDGES);

    // scan deg -> row_start (+cursor), dinv folded into pass 1
    k_scan1<<<N_SCAN_BLKS, SCAN_BLK, 0, stream>>>(deg, excl, blk_sum, dinv, N_NODES);
    k_scan2<<<1, SCAN_BLK, 0, stream>>>(blk_sum, blk_off, N_SCAN_BLKS);
    k_scan3<<<(N_NODES + 255) / 256, 256, 0, stream>>>(excl, blk_off, row_start, cursor,
                                                       N_NODES, N_EDGES);

    // CSR fill (packed)
    k_fill<<<(N_EDGES + 255) / 256, 256, 0, stream>>>(src, dst, dinv, cursor, csr, N_EDGES);

    // fused weights, then project x down to 40 feats BEFORE propagation
    k_fuse_w<<<(D * NC + NC + 255) / 256, 256, 0, stream>>>(Wsgc, bsgc, Wcls, bcls, Wf, bf);
    k_proj<<<(N_NODES + 63) / 64, 320, 0, stream>>>(x, Wf, z0, N_NODES);

    // 2 hops on 40-wide features; hop 2 fuses bias and writes d_out directly
    k_pull40<<<(N_NODES + 23) / 24, 256, 0, stream>>>(row_start, csr, dinv, z0, z1,
                                                      nullptr, N_NODES);
    k_pull40<<<(N_NODES + 23) / 24, 256, 0, stream>>>(row_start, csr, dinv, z1, out,
                                                      bf, N_NODES);
}

// Round 5
// 167.015 us; speedup vs baseline: 1.1098x; 1.1098x over previous
//
#include <hip/hip_runtime.h>

#define N_NODES 50000
#define N_EDGES 600000
#define D 128
#define NC 40
#define SCAN_BLK 256
#define N_SCAN_BLKS ((N_NODES + SCAN_BLK - 1) / SCAN_BLK)  // 196 <= 256
#define EDGE_BLKS ((N_EDGES + 255) / 256)                  // 2344
#define FUSE_ELEMS (D * NC + NC)
#define FUSE_BLKS ((FUSE_ELEMS + 255) / 256)               // 21

// ---------------- degree count + fused-weight precompute (merged) ----------------
// Blocks [0, EDGE_BLKS): atomic degree count over dst.
// Blocks [EDGE_BLKS, EDGE_BLKS+FUSE_BLKS): Wf = W_sgc @ W_cls, bf = b_sgc @ W_cls + b_cls.

__global__ void k_deg_fuse(const int* __restrict__ dst, int* __restrict__ deg,
                           const float* __restrict__ Wsgc, const float* __restrict__ bsgc,
                           const float* __restrict__ Wcls, const float* __restrict__ bcls,
                           float* __restrict__ Wf, float* __restrict__ bf) {
    if (blockIdx.x < EDGE_BLKS) {
        int e = blockIdx.x * 256 + threadIdx.x;
        if (e < N_EDGES) atomicAdd(&deg[dst[e]], 1);
    } else {
        int idx = (blockIdx.x - EDGE_BLKS) * 256 + threadIdx.x;
        if (idx < D * NC) {
            int k = idx / NC, c = idx % NC;
            float acc = 0.f;
            for (int j = 0; j < D; j++) acc += Wsgc[k * D + j] * Wcls[j * NC + c];
            Wf[idx] = acc;
        } else if (idx < FUSE_ELEMS) {
            int c = idx - D * NC;
            float acc = bcls[c];
            for (int j = 0; j < D; j++) acc += bsgc[j] * Wcls[j * NC + c];
            bf[c] = acc;
        }
    }
}

// ---------------- scan (3-kernel) + dinv folded into pass 1 ----------------

__global__ void k_scan1(const int* __restrict__ deg, int* __restrict__ excl,
                        int* __restrict__ blk_sum, float* __restrict__ dinv, int nN) {
    __shared__ int lds[SCAN_BLK];
    int t = threadIdx.x;
    int i = blockIdx.x * SCAN_BLK + t;
    int v = (i < nN) ? deg[i] : 0;
    if (i < nN) dinv[i] = rsqrtf((float)v + 1.0f);  // +1 = self-loop
    lds[t] = v;
    __syncthreads();
    for (int offs = 1; offs < SCAN_BLK; offs <<= 1) {
        int add = (t >= offs) ? lds[t - offs] : 0;
        __syncthreads();
        lds[t] += add;
        __syncthreads();
    }
    if (i < nN) excl[i] = lds[t] - v;
    if (t == SCAN_BLK - 1) blk_sum[blockIdx.x] = lds[t];
}

__global__ void k_scan2(const int* __restrict__ blk_sum, int* __restrict__ blk_off, int nB) {
    __shared__ int lds[SCAN_BLK];
    int t = threadIdx.x;
    int v = (t < nB) ? blk_sum[t] : 0;
    lds[t] = v;
    __syncthreads();
    for (int offs = 1; offs < SCAN_BLK; offs <<= 1) {
        int add = (t >= offs) ? lds[t - offs] : 0;
        __syncthreads();
        lds[t] += add;
        __syncthreads();
    }
    if (t < nB) blk_off[t] = lds[t] - v;
}

__global__ void k_scan3(const int* __restrict__ excl, const int* __restrict__ blk_off,
                        int* __restrict__ row_start, int* __restrict__ cursor, int nN, int nE) {
    int i = blockIdx.x * blockDim.x + threadIdx.x;
    if (i < nN) {
        int r = excl[i] + blk_off[i / SCAN_BLK];
        row_start[i] = r;
        cursor[i] = r;
    }
    if (i == 0) row_start[nN] = nE;
}

// ---------------- CSR fill (by dst), packed {src, w} ----------------

__global__ void k_fill(const int* __restrict__ src, const int* __restrict__ dst,
                       const float* __restrict__ dinv, int* __restrict__ cursor,
                       int2* __restrict__ csr, int nE) {
    int e = blockIdx.x * blockDim.x + threadIdx.x;
    if (e >= nE) return;
    int s = src[e], d = dst[e];
    float w = dinv[s] * dinv[d];
    int pos = atomicAdd(&cursor[d], 1);
    csr[pos] = make_int2(s, __float_as_int(w));
}

// ---------------- projection: z = x @ Wf  (50000x128 @ 128x40) ----------------
// 320 threads = 5 waves, 64-node tile. x tile staged in LDS (coalesced, +1 pad ->
// compute read sX[lane][k] is 2-way bank aliasing = free). W read from global with
// wave-uniform addresses (1 L1 tx per load, 20 KB L1-resident). Wave w owns cols
// [w*8, w*8+8); lane = node. 8 FMA : 1 LDS-read per k -> VALU-limited.

__global__ __launch_bounds__(320) void k_proj(const float* __restrict__ x,
                                              const float* __restrict__ Wf,
                                              float* __restrict__ z, int nN) {
    __shared__ float sX[64][D + 1];  // stride 129: bank (lane+k)%32, 2-way = free
    int t = threadIdx.x;
    int base = blockIdx.x * 64;
    int rows = nN - base;
    if (rows > 64) rows = 64;
    const float* xs = x + (size_t)base * D;
    for (int idx = t; idx < rows * D; idx += 320) {
        sX[idx >> 7][idx & 127] = xs[idx];
    }
    __syncthreads();
    int lane = t & 63;
    int wv = t >> 6;             // 0..4
    int c0 = wv * 8;
    int node = base + lane;
    if (node >= nN) return;
    float a0 = 0.f, a1 = 0.f, a2 = 0.f, a3 = 0.f;
    float a4 = 0.f, a5 = 0.f, a6 = 0.f, a7 = 0.f;
#pragma unroll 8
    for (int k = 0; k < D; k++) {
        float xv = sX[lane][k];
        const float* wr = Wf + (size_t)k * NC + c0;   // wave-uniform address
        float4 wA = *reinterpret_cast<const float4*>(wr);
        float4 wB = *reinterpret_cast<const float4*>(wr + 4);
        a0 += xv * wA.x; a1 += xv * wA.y; a2 += xv * wA.z; a3 += xv * wA.w;
        a4 += xv * wB.x; a5 += xv * wB.y; a6 += xv * wB.z; a7 += xv * wB.w;
    }
    float* zo = z + (size_t)node * NC + c0;
    *reinterpret_cast<float4*>(zo) = make_float4(a0, a1, a2, a3);
    *reinterpret_cast<float4*>(zo + 4) = make_float4(a4, a5, a6, a7);
}

// ---------------- pull propagation on 40-wide features ----------------
// hout[i] = dinv[i]^2 * hin[i] + sum_j w_j * hin[src_j]   (+ optional bias)
// 10 lanes x float4 per node; 6 groups per wave; 24 nodes per 256-thread block.

__global__ void k_pull40(const int* __restrict__ row_start, const int2* __restrict__ csr,
                         const float* __restrict__ dinv,
                         const float* __restrict__ hin, float* __restrict__ hout,
                         const float* __restrict__ bias, int nN) {
    int wave = threadIdx.x >> 6;
    int lane = threadIdx.x & 63;
    int g = lane / 10;            // 0..5, g==6 idle (lanes 60..63)
    int l = lane - g * 10;
    int node = blockIdx.x * 24 + wave * 6 + g;
    if (g >= 6 || node >= nN) return;
    int f = l << 2;               // feat 0..36
    float s = dinv[node];
    s = s * s;
    float4 acc = *reinterpret_cast<const float4*>(hin + (size_t)node * NC + f);
    acc.x *= s; acc.y *= s; acc.z *= s; acc.w *= s;
    int j = row_start[node], end = row_start[node + 1];
    for (; j + 2 <= end; j += 2) {
        int2 e0 = csr[j], e1 = csr[j + 1];
        float w0 = __int_as_float(e0.y), w1 = __int_as_float(e1.y);
        float4 v0 = *reinterpret_cast<const float4*>(hin + (size_t)e0.x * NC + f);
        float4 v1 = *reinterpret_cast<const float4*>(hin + (size_t)e1.x * NC + f);
        acc.x += w0 * v0.x; acc.y += w0 * v0.y; acc.z += w0 * v0.z; acc.w += w0 * v0.w;
        acc.x += w1 * v1.x; acc.y += w1 * v1.y; acc.z += w1 * v1.z; acc.w += w1 * v1.w;
    }
    if (j < end) {
        int2 e0 = csr[j];
        float w0 = __int_as_float(e0.y);
        float4 v0 = *reinterpret_cast<const float4*>(hin + (size_t)e0.x * NC + f);
        acc.x += w0 * v0.x; acc.y += w0 * v0.y; acc.z += w0 * v0.z; acc.w += w0 * v0.w;
    }
    if (bias) {
        float4 b = *reinterpret_cast<const float4*>(bias + f);
        acc.x += b.x; acc.y += b.y; acc.z += b.z; acc.w += b.w;
    }
    *reinterpret_cast<float4*>(hout + (size_t)node * NC + f) = acc;
}

// ---------------- launch ----------------

extern "C" void kernel_launch(void* const* d_in, const int* in_sizes, int n_in,
                              void* d_out, int out_size, void* d_ws, size_t ws_size,
                              hipStream_t stream) {
    const float* x    = (const float*)d_in[0];
    const int*   ei   = (const int*)d_in[1];   // [2, E] flat: row0=src, row1=dst
    const float* Wsgc = (const float*)d_in[2];
    const float* bsgc = (const float*)d_in[3];
    const float* Wcls = (const float*)d_in[4];
    const float* bcls = (const float*)d_in[5];
    float* out = (float*)d_out;

    const int* src = ei;
    const int* dst = ei + N_EDGES;

    char* ws = (char*)d_ws;
    size_t off = 0;
    auto alloc = [&](size_t bytes) -> void* {
        void* p = ws + off;
        off += (bytes + 255) & ~255ull;
        return p;
    };
    int*   deg      = (int*)alloc((size_t)N_NODES * 4);
    float* dinv     = (float*)alloc((size_t)N_NODES * 4);
    int*   excl     = (int*)alloc((size_t)N_NODES * 4);
    int*   blk_sum  = (int*)alloc((size_t)SCAN_BLK * 4);
    int*   blk_off  = (int*)alloc((size_t)SCAN_BLK * 4);
    int*   row_start= (int*)alloc((size_t)(N_NODES + 1) * 4);
    int*   cursor   = (int*)alloc((size_t)N_NODES * 4);
    int2*  csr      = (int2*)alloc((size_t)N_EDGES * 8);
    float* z0       = (float*)alloc((size_t)N_NODES * NC * 4);
    float* z1       = (float*)alloc((size_t)N_NODES * NC * 4);
    float* Wf       = (float*)alloc((size_t)D * NC * 4);
    float* bf       = (float*)alloc((size_t)NC * 4);

    hipMemsetAsync(deg, 0, (size_t)N_NODES * 4, stream);

    // degree count + fused-weight precompute in one dispatch
    k_deg_fuse<<<EDGE_BLKS + FUSE_BLKS, 256, 0, stream>>>(dst, deg, Wsgc, bsgc, Wcls, bcls,
                                                          Wf, bf);

    // scan deg -> row_start (+cursor), dinv folded into pass 1
    k_scan1<<<N_SCAN_BLKS, SCAN_BLK, 0, stream>>>(deg, excl, blk_sum, dinv, N_NODES);
    k_scan2<<<1, SCAN_BLK, 0, stream>>>(blk_sum, blk_off, N_SCAN_BLKS);
    k_scan3<<<(N_NODES + 255) / 256, 256, 0, stream>>>(excl, blk_off, row_start, cursor,
                                                       N_NODES, N_EDGES);

    // CSR fill (packed)
    k_fill<<<EDGE_BLKS, 256, 0, stream>>>(src, dst, dinv, cursor, csr, N_EDGES);

    // project x down to 40 feats BEFORE propagation
    k_proj<<<(N_NODES + 63) / 64, 320, 0, stream>>>(x, Wf, z0, N_NODES);

    // 2 hops on 40-wide features; hop 2 fuses bias and writes d_out directly
    k_pull40<<<(N_NODES + 23) / 24, 256, 0, stream>>>(row_start, csr, dinv, z0, z1,
                                                      nullptr, N_NODES);
    k_pull40<<<(N_NODES + 23) / 24, 256, 0, stream>>>(row_start, csr, dinv, z1, out,
                                                      bf, N_NODES);
}

// Round 6
// 143.996 us; speedup vs baseline: 1.2872x; 1.1599x over previous
//
#include <hip/hip_runtime.h>

#define N_NODES 50000
#define N_EDGES 600000
#define D 128
#define NC 40
#define SCAN_BLK 256
#define N_SCAN_BLKS ((N_NODES + SCAN_BLK - 1) / SCAN_BLK)  // 196 <= 256
#define EDGE_BLKS ((N_EDGES + 255) / 256)                  // 2344
#define FUSE_ELEMS (D * NC + NC)
#define FUSE_BLKS ((FUSE_ELEMS + 255) / 256)               // 21

// ---------------- degree count + fused-weight precompute (merged) ----------------

__global__ void k_deg_fuse(const int* __restrict__ dst, int* __restrict__ deg,
                           const float* __restrict__ Wsgc, const float* __restrict__ bsgc,
                           const float* __restrict__ Wcls, const float* __restrict__ bcls,
                           float* __restrict__ Wf, float* __restrict__ bf) {
    if (blockIdx.x < EDGE_BLKS) {
        int e = blockIdx.x * 256 + threadIdx.x;
        if (e < N_EDGES) atomicAdd(&deg[dst[e]], 1);
    } else {
        int idx = (blockIdx.x - EDGE_BLKS) * 256 + threadIdx.x;
        if (idx < D * NC) {
            int k = idx / NC, c = idx % NC;
            float acc = 0.f;
            for (int j = 0; j < D; j++) acc += Wsgc[k * D + j] * Wcls[j * NC + c];
            Wf[idx] = acc;
        } else if (idx < FUSE_ELEMS) {
            int c = idx - D * NC;
            float acc = bcls[c];
            for (int j = 0; j < D; j++) acc += bsgc[j] * Wcls[j * NC + c];
            bf[c] = acc;
        }
    }
}

// ---------------- scan (3-kernel) + dinv folded into pass 1 ----------------

__global__ void k_scan1(const int* __restrict__ deg, int* __restrict__ excl,
                        int* __restrict__ blk_sum, float* __restrict__ dinv, int nN) {
    __shared__ int lds[SCAN_BLK];
    int t = threadIdx.x;
    int i = blockIdx.x * SCAN_BLK + t;
    int v = (i < nN) ? deg[i] : 0;
    if (i < nN) dinv[i] = rsqrtf((float)v + 1.0f);  // +1 = self-loop
    lds[t] = v;
    __syncthreads();
    for (int offs = 1; offs < SCAN_BLK; offs <<= 1) {
        int add = (t >= offs) ? lds[t - offs] : 0;
        __syncthreads();
        lds[t] += add;
        __syncthreads();
    }
    if (i < nN) excl[i] = lds[t] - v;
    if (t == SCAN_BLK - 1) blk_sum[blockIdx.x] = lds[t];
}

__global__ void k_scan2(const int* __restrict__ blk_sum, int* __restrict__ blk_off, int nB) {
    __shared__ int lds[SCAN_BLK];
    int t = threadIdx.x;
    int v = (t < nB) ? blk_sum[t] : 0;
    lds[t] = v;
    __syncthreads();
    for (int offs = 1; offs < SCAN_BLK; offs <<= 1) {
        int add = (t >= offs) ? lds[t - offs] : 0;
        __syncthreads();
        lds[t] += add;
        __syncthreads();
    }
    if (t < nB) blk_off[t] = lds[t] - v;
}

__global__ void k_scan3(const int* __restrict__ excl, const int* __restrict__ blk_off,
                        int* __restrict__ row_start, int* __restrict__ cursor, int nN, int nE) {
    int i = blockIdx.x * blockDim.x + threadIdx.x;
    if (i < nN) {
        int r = excl[i] + blk_off[i / SCAN_BLK];
        row_start[i] = r;
        cursor[i] = r;
    }
    if (i == 0) row_start[nN] = nE;
}

// ---------------- CSR fill (by dst), packed {src, w} ----------------

__global__ void k_fill(const int* __restrict__ src, const int* __restrict__ dst,
                       const float* __restrict__ dinv, int* __restrict__ cursor,
                       int2* __restrict__ csr, int nE) {
    int e = blockIdx.x * blockDim.x + threadIdx.x;
    if (e >= nE) return;
    int s = src[e], d = dst[e];
    float w = dinv[s] * dinv[d];
    int pos = atomicAdd(&cursor[d], 1);
    csr[pos] = make_int2(s, __float_as_int(w));
}

// ---------------- projection: z = x @ Wf  (50000x128 @ 128x40) ----------------
// 320 threads = 5 waves, 64-node tile. BOTH operands in LDS: x tile (stride-129 pad ->
// read sX[lane][k] is 2-way aliasing = free) and W (20 KB; in-loop reads are
// wave-uniform -> LDS broadcast, conflict-free). The k-loop touches no global/scalar
// memory: 1 ds_read_b32 + 2 ds_read_b128 + 8 FMA per k. 53 KB LDS -> 3 blocks/CU,
// grid of 782 fully resident.

__global__ __launch_bounds__(320) void k_proj(const float* __restrict__ x,
                                              const float* __restrict__ Wf,
                                              float* __restrict__ z, int nN) {
    __shared__ float sW[D * NC];     // 20.5 KB
    __shared__ float sX[64][D + 1];  // 33 KB; bank (lane+k)%32
    int t = threadIdx.x;
    // stage W: 1280 float4, coalesced
    {
        const float4* w4 = reinterpret_cast<const float4*>(Wf);
        float4* s4 = reinterpret_cast<float4*>(sW);
#pragma unroll
        for (int i = 0; i < 4; i++) s4[t + 320 * i] = w4[t + 320 * i];
    }
    // stage x tile: coalesced 4B global loads, conflict-free LDS writes
    int base = blockIdx.x * 64;
    int rows = nN - base;
    if (rows > 64) rows = 64;
    const float* xs = x + (size_t)base * D;
    for (int idx = t; idx < rows * D; idx += 320)
        sX[idx >> 7][idx & 127] = xs[idx];
    __syncthreads();
    int lane = t & 63;
    int wv = t >> 6;             // 0..4
    int c0 = wv * 8;
    int node = base + lane;
    if (node >= nN) return;
    float a0 = 0.f, a1 = 0.f, a2 = 0.f, a3 = 0.f;
    float a4 = 0.f, a5 = 0.f, a6 = 0.f, a7 = 0.f;
#pragma unroll 4
    for (int k = 0; k < D; k++) {
        float xv = sX[lane][k];
        const float* wr = sW + k * NC + c0;   // wave-uniform -> LDS broadcast
        float4 wA = *reinterpret_cast<const float4*>(wr);
        float4 wB = *reinterpret_cast<const float4*>(wr + 4);
        a0 += xv * wA.x; a1 += xv * wA.y; a2 += xv * wA.z; a3 += xv * wA.w;
        a4 += xv * wB.x; a5 += xv * wB.y; a6 += xv * wB.z; a7 += xv * wB.w;
    }
    float* zo = z + (size_t)node * NC + c0;
    *reinterpret_cast<float4*>(zo) = make_float4(a0, a1, a2, a3);
    *reinterpret_cast<float4*>(zo + 4) = make_float4(a4, a5, a6, a7);
}

// ---------------- pull propagation on 40-wide features ----------------

__global__ void k_pull40(const int* __restrict__ row_start, const int2* __restrict__ csr,
                         const float* __restrict__ dinv,
                         const float* __restrict__ hin, float* __restrict__ hout,
                         const float* __restrict__ bias, int nN) {
    int wave = threadIdx.x >> 6;
    int lane = threadIdx.x & 63;
    int g = lane / 10;            // 0..5, g==6 idle (lanes 60..63)
    int l = lane - g * 10;
    int node = blockIdx.x * 24 + wave * 6 + g;
    if (g >= 6 || node >= nN) return;
    int f = l << 2;               // feat 0..36
    float s = dinv[node];
    s = s * s;
    float4 acc = *reinterpret_cast<const float4*>(hin + (size_t)node * NC + f);
    acc.x *= s; acc.y *= s; acc.z *= s; acc.w *= s;
    int j = row_start[node], end = row_start[node + 1];
    for (; j + 2 <= end; j += 2) {
        int2 e0 = csr[j], e1 = csr[j + 1];
        float w0 = __int_as_float(e0.y), w1 = __int_as_float(e1.y);
        float4 v0 = *reinterpret_cast<const float4*>(hin + (size_t)e0.x * NC + f);
        float4 v1 = *reinterpret_cast<const float4*>(hin + (size_t)e1.x * NC + f);
        acc.x += w0 * v0.x; acc.y += w0 * v0.y; acc.z += w0 * v0.z; acc.w += w0 * v0.w;
        acc.x += w1 * v1.x; acc.y += w1 * v1.y; acc.z += w1 * v1.z; acc.w += w1 * v1.w;
    }
    if (j < end) {
        int2 e0 = csr[j];
        float w0 = __int_as_float(e0.y);
        float4 v0 = *reinterpret_cast<const float4*>(hin + (size_t)e0.x * NC + f);
        acc.x += w0 * v0.x; acc.y += w0 * v0.y; acc.z += w0 * v0.z; acc.w += w0 * v0.w;
    }
    if (bias) {
        float4 b = *reinterpret_cast<const float4*>(bias + f);
        acc.x += b.x; acc.y += b.y; acc.z += b.z; acc.w += b.w;
    }
    *reinterpret_cast<float4*>(hout + (size_t)node * NC + f) = acc;
}

// ---------------- launch ----------------

extern "C" void kernel_launch(void* const* d_in, const int* in_sizes, int n_in,
                              void* d_out, int out_size, void* d_ws, size_t ws_size,
                              hipStream_t stream) {
    const float* x    = (const float*)d_in[0];
    const int*   ei   = (const int*)d_in[1];   // [2, E] flat: row0=src, row1=dst
    const float* Wsgc = (const float*)d_in[2];
    const float* bsgc = (const float*)d_in[3];
    const float* Wcls = (const float*)d_in[4];
    const float* bcls = (const float*)d_in[5];
    float* out = (float*)d_out;

    const int* src = ei;
    const int* dst = ei + N_EDGES;

    char* ws = (char*)d_ws;
    size_t off = 0;
    auto alloc = [&](size_t bytes) -> void* {
        void* p = ws + off;
        off += (bytes + 255) & ~255ull;
        return p;
    };
    int*   deg      = (int*)alloc((size_t)N_NODES * 4);
    float* dinv     = (float*)alloc((size_t)N_NODES * 4);
    int*   excl     = (int*)alloc((size_t)N_NODES * 4);
    int*   blk_sum  = (int*)alloc((size_t)SCAN_BLK * 4);
    int*   blk_off  = (int*)alloc((size_t)SCAN_BLK * 4);
    int*   row_start= (int*)alloc((size_t)(N_NODES + 1) * 4);
    int*   cursor   = (int*)alloc((size_t)N_NODES * 4);
    int2*  csr      = (int2*)alloc((size_t)N_EDGES * 8);
    float* z0       = (float*)alloc((size_t)N_NODES * NC * 4);
    float* z1       = (float*)alloc((size_t)N_NODES * NC * 4);
    float* Wf       = (float*)alloc((size_t)D * NC * 4);
    float* bf       = (float*)alloc((size_t)NC * 4);

    hipMemsetAsync(deg, 0, (size_t)N_NODES * 4, stream);

    // degree count + fused-weight precompute in one dispatch
    k_deg_fuse<<<EDGE_BLKS + FUSE_BLKS, 256, 0, stream>>>(dst, deg, Wsgc, bsgc, Wcls, bcls,
                                                          Wf, bf);

    // scan deg -> row_start (+cursor), dinv folded into pass 1
    k_scan1<<<N_SCAN_BLKS, SCAN_BLK, 0, stream>>>(deg, excl, blk_sum, dinv, N_NODES);
    k_scan2<<<1, SCAN_BLK, 0, stream>>>(blk_sum, blk_off, N_SCAN_BLKS);
    k_scan3<<<(N_NODES + 255) / 256, 256, 0, stream>>>(excl, blk_off, row_start, cursor,
                                                       N_NODES, N_EDGES);

    // CSR fill (packed)
    k_fill<<<EDGE_BLKS, 256, 0, stream>>>(src, dst, dinv, cursor, csr, N_EDGES);

    // project x down to 40 feats BEFORE propagation
    k_proj<<<(N_NODES + 63) / 64, 320, 0, stream>>>(x, Wf, z0, N_NODES);

    // 2 hops on 40-wide features; hop 2 fuses bias and writes d_out directly
    k_pull40<<<(N_NODES + 23) / 24, 256, 0, stream>>>(row_start, csr, dinv, z0, z1,
                                                      nullptr, N_NODES);
    k_pull40<<<(N_NODES + 23) / 24, 256, 0, stream>>>(row_start, csr, dinv, z1, out,
                                                      bf, N_NODES);
}